// Round 14
// baseline (431.688 us; speedup 1.0000x reference)
//
#include <hip/hip_runtime.h>
#include <math.h>

#define EMBED 768
#define DI 1536
#define DSTATE 16
#define DCONV 4
#define DTRANK 48
#define FF 3072
#define BATCH 2
#define SEQ 1024
#define NROWS (BATCH*SEQ)
#define TCH 32
#define NCH (SEQ/TCH)

typedef __bf16 bf16x8 __attribute__((ext_vector_type(8)));
typedef float f32x4 __attribute__((ext_vector_type(4)));
typedef unsigned int u32x4 __attribute__((ext_vector_type(4)));

static __device__ __forceinline__ unsigned short f2b(float f) {
    union { float f; unsigned u; } v; v.f = f;
    unsigned r = v.u + 0x7FFFu + ((v.u >> 16) & 1u);
    return (unsigned short)(r >> 16);
}
static __device__ __forceinline__ float b2f(unsigned short s) {
    union { unsigned u; float f; } v; v.u = ((unsigned)s) << 16;
    return v.f;
}

#define GLOAD_LDS16(g, l) __builtin_amdgcn_global_load_lds( \
    (const __attribute__((address_space(1))) void*)(g), \
    (__attribute__((address_space(3))) void*)(l), 16, 0, 0)

// ---------------------------------------------------------------------------
// gemm_sk: C[M,N] = A[M,K](bf16) @ W[N,K](bf16)^T, 128x64 tile, BK=32,
// 2-phase double-buffered global_load_lds staging.
// EPI: 3 gelu(acc+bias)->Cb bf16 ; 6 plain bf16 -> Cb ; KSPLIT>1 -> partials.
// ---------------------------------------------------------------------------
template<int EPI, int KSPLIT>
__global__ __launch_bounds__(256)
void gemm_sk(const unsigned short* __restrict__ A,
             const unsigned short* __restrict__ W,
             float* __restrict__ C, unsigned short* __restrict__ Cb,
             float* __restrict__ part,
             int M, int N, int K,
             const float* __restrict__ bias)
{
    __shared__ alignas(16) unsigned short As[2][128 * 32];
    __shared__ alignas(16) unsigned short Ws[2][64 * 32];
    const int tid  = threadIdx.x;
    const int lane = tid & 63, wave = tid >> 6;
    const int bm = blockIdx.y * 128, bn = blockIdx.x * 64;
    const int kc = K / KSPLIT;
    const int kz = blockIdx.z * kc;
    const int ln = lane & 15, lg = lane >> 4;

    f32x4 acc[2][4];
    #pragma unroll
    for (int i = 0; i < 2; ++i)
        #pragma unroll
        for (int j = 0; j < 4; ++j)
            acc[i][j] = (f32x4){0.f, 0.f, 0.f, 0.f};

    const int ra = tid >> 2, ca = tid & 3;
    const int cs = (ca * 8) ^ ((ra & 3) << 3);
    const unsigned short* gA0 = A + (size_t)(bm + ra) * K + kz + cs;
    const unsigned short* gA1 = A + (size_t)(bm + ra + 64) * K + kz + cs;
    const unsigned short* gW  = W + (size_t)(bn + ra) * K + kz + cs;

#define STAGE(bf, kk) do { \
        GLOAD_LDS16(gA0 + (kk), &As[bf][wave * 512]); \
        GLOAD_LDS16(gA1 + (kk), &As[bf][2048 + wave * 512]); \
        GLOAD_LDS16(gW  + (kk), &Ws[bf][wave * 512]); \
    } while (0)

    STAGE(0, 0);
    __syncthreads();
    int buf = 0;
    for (int k0 = 0; k0 < kc; k0 += 32) {
        if (k0 + 32 < kc) STAGE(buf ^ 1, k0 + 32);
        bf16x8 af[2], wf[4];
        #pragma unroll
        for (int i = 0; i < 2; ++i) {
            int row = wave * 32 + i * 16 + ln;
            af[i] = *reinterpret_cast<const bf16x8*>(
                &As[buf][row * 32 + ((lg * 8) ^ ((row & 3) << 3))]);
        }
        #pragma unroll
        for (int j = 0; j < 4; ++j) {
            int row = j * 16 + ln;
            wf[j] = *reinterpret_cast<const bf16x8*>(
                &Ws[buf][row * 32 + ((lg * 8) ^ ((row & 3) << 3))]);
        }
        #pragma unroll
        for (int i = 0; i < 2; ++i)
            #pragma unroll
            for (int j = 0; j < 4; ++j)
                acc[i][j] = __builtin_amdgcn_mfma_f32_16x16x32_bf16(af[i], wf[j], acc[i][j], 0, 0, 0);
        __syncthreads();
        buf ^= 1;
    }
#undef STAGE

    if constexpr (KSPLIT > 1) {
        float* pb = part + (size_t)blockIdx.z * M * N;
        #pragma unroll
        for (int i = 0; i < 2; ++i)
            #pragma unroll
            for (int j = 0; j < 4; ++j) {
                int col = bn + j * 16 + ln;
                #pragma unroll
                for (int rr = 0; rr < 4; ++rr) {
                    int row = bm + wave * 32 + i * 16 + lg * 4 + rr;
                    pb[(size_t)row * N + col] = acc[i][j][rr];
                }
            }
    } else {
        #pragma unroll
        for (int i = 0; i < 2; ++i)
            #pragma unroll
            for (int j = 0; j < 4; ++j) {
                int col = bn + j * 16 + ln;
                #pragma unroll
                for (int rr = 0; rr < 4; ++rr) {
                    int row = bm + wave * 32 + i * 16 + lg * 4 + rr;
                    float v = acc[i][j][rr];
                    size_t o = (size_t)row * N + col;
                    if (EPI == 3) {
                        v += bias[col];
                        float t = 0.7978845608028654f * (v + 0.044715f * v * v * v);
                        Cb[o] = f2b(0.5f * v * (1.f + tanhf(t)));
                    } else if (EPI == 6) {
                        Cb[o] = f2b(v);
                    } else {
                        C[o] = v;
                    }
                }
            }
    }
}

// ---------------------------------------------------------------------------
// reduce_ln: sum KS split-K partials (+bias) (+resid), then LayerNorm(768).
// ---------------------------------------------------------------------------
template<int KS, int BIAS>
__global__ __launch_bounds__(256)
void reduce_ln(const float* __restrict__ part, const float* __restrict__ resid,
               const float* __restrict__ bias,
               const float* __restrict__ w, const float* __restrict__ bb,
               float* __restrict__ out, unsigned short* __restrict__ outb)
{
    const int row = blockIdx.x;
    const size_t ro = (size_t)row * EMBED;
    const int i0 = threadIdx.x, i1 = i0 + 256, i2 = i0 + 512;
    float v0 = 0.f, v1 = 0.f, v2 = 0.f;
    #pragma unroll
    for (int z = 0; z < KS; ++z) {
        const float* p = part + (size_t)z * NROWS * EMBED + ro;
        v0 += p[i0]; v1 += p[i1]; v2 += p[i2];
    }
    if (BIAS) { v0 += bias[i0]; v1 += bias[i1]; v2 += bias[i2]; }
    v0 += resid[ro + i0]; v1 += resid[ro + i1]; v2 += resid[ro + i2];

    float s  = v0 + v1 + v2;
    float s2 = v0 * v0 + v1 * v1 + v2 * v2;
    #pragma unroll
    for (int m = 1; m < 64; m <<= 1) {
        s  += __shfl_xor(s,  m);
        s2 += __shfl_xor(s2, m);
    }
    __shared__ float sh1[4], sh2[4];
    int wv = threadIdx.x >> 6;
    if ((threadIdx.x & 63) == 0) { sh1[wv] = s; sh2[wv] = s2; }
    __syncthreads();
    float S1 = sh1[0] + sh1[1] + sh1[2] + sh1[3];
    float S2 = sh2[0] + sh2[1] + sh2[2] + sh2[3];
    float mu  = S1 * (1.f / EMBED);
    float var = S2 * (1.f / EMBED) - mu * mu;
    float rs  = rsqrtf(var + 1e-5f);
    float o0 = (v0 - mu) * rs * w[i0] + bb[i0];
    float o1 = (v1 - mu) * rs * w[i1] + bb[i1];
    float o2 = (v2 - mu) * rs * w[i2] + bb[i2];
    out[ro + i0] = o0; out[ro + i1] = o1; out[ro + i2] = o2;
    if (outb) {
        outb[ro + i0] = f2b(o0); outb[ro + i1] = f2b(o1); outb[ro + i2] = f2b(o2);
    }
}

// ---------------------------------------------------------------------------
// x_proj split-K MFMA + reduce
// ---------------------------------------------------------------------------
__global__ __launch_bounds__(256)
void xproj_mfma(const unsigned short* __restrict__ A,
                const unsigned short* __restrict__ W,
                float* __restrict__ part)
{
    const int mt = blockIdx.x, s = blockIdx.y;
    const int lane = threadIdx.x & 63, wave = threadIdx.x >> 6;
    const int ln = lane & 15, lg = lane >> 4;
    const int row0 = mt * 128 + wave * 32;
    const int kb = s * 192;
    f32x4 acc[2][5];
    #pragma unroll
    for (int i = 0; i < 2; ++i)
        #pragma unroll
        for (int j = 0; j < 5; ++j)
            acc[i][j] = (f32x4){0.f, 0.f, 0.f, 0.f};

    for (int kk = 0; kk < 192; kk += 32) {
        const int k = kb + kk + lg * 8;
        bf16x8 af[2], wf[5];
        af[0] = *reinterpret_cast<const bf16x8*>(A + (size_t)(row0 + ln) * DI + k);
        af[1] = *reinterpret_cast<const bf16x8*>(A + (size_t)(row0 + 16 + ln) * DI + k);
        #pragma unroll
        for (int j = 0; j < 5; ++j)
            wf[j] = *reinterpret_cast<const bf16x8*>(W + (size_t)(j * 16 + ln) * DI + k);
        #pragma unroll
        for (int i = 0; i < 2; ++i)
            #pragma unroll
            for (int j = 0; j < 5; ++j)
                acc[i][j] = __builtin_amdgcn_mfma_f32_16x16x32_bf16(af[i], wf[j], acc[i][j], 0, 0, 0);
    }
    float* pb = part + (size_t)s * NROWS * 80;
    #pragma unroll
    for (int i = 0; i < 2; ++i)
        #pragma unroll
        for (int j = 0; j < 5; ++j)
            #pragma unroll
            for (int rr = 0; rr < 4; ++rr) {
                int row = row0 + i * 16 + lg * 4 + rr;
                int col = j * 16 + ln;
                pb[(size_t)row * 80 + col] = acc[i][j][rr];
            }
}

__global__ __launch_bounds__(256)
void xproj_reduce(const float* __restrict__ part, float* __restrict__ xdbl,
                  unsigned short* __restrict__ xdblb)
{
    int idx = blockIdx.x * 256 + threadIdx.x;      // 163840
    float sum = 0.f;
    #pragma unroll
    for (int s = 0; s < 8; ++s) sum += part[(size_t)s * NROWS * 80 + idx];
    xdbl[idx] = sum;
    int col = idx % 80, row = idx / 80;
    if (col < 48)      xdblb[row * 64 + col] = f2b(sum);
    else if (col < 64) xdblb[row * 64 + col] = 0;
}

// ---------------------------------------------------------------------------
// f32 -> bf16 conversion: x + 4 big weights + x_proj_w + padded dt_proj_w.
// ---------------------------------------------------------------------------
__global__ __launch_bounds__(256)
void cvt7_k(const float* __restrict__ x,  const float* __restrict__ w1,
            const float* __restrict__ w2, const float* __restrict__ w3,
            const float* __restrict__ w4, const float* __restrict__ w5,
            const float* __restrict__ w6,
            unsigned short* __restrict__ xb,  unsigned short* __restrict__ w1b,
            unsigned short* __restrict__ w2b, unsigned short* __restrict__ w3b,
            unsigned short* __restrict__ w4b, unsigned short* __restrict__ w5b,
            unsigned short* __restrict__ w6b)
{
    size_t i4 = ((size_t)blockIdx.x * 256 + threadIdx.x) * 4;
    if (i4 >= 9953280u) {
        int off = (int)(i4 - 9953280u);
        if (off >= 98304) return;
        int row = off >> 6, colb = off & 63;
        ushort4 u = {0, 0, 0, 0};
        if (colb < 48) {
            float4 v = *reinterpret_cast<const float4*>(w6 + row * 48 + colb);
            u.x = f2b(v.x); u.y = f2b(v.y); u.z = f2b(v.z); u.w = f2b(v.w);
        }
        *reinterpret_cast<ushort4*>(w6b + off) = u;
        return;
    }
    const float* src; unsigned short* dst; size_t off;
    if      (i4 < 1572864u) { src = x;  dst = xb;  off = i4; }
    else if (i4 < 3932160u) { src = w1; dst = w1b; off = i4 - 1572864u; }
    else if (i4 < 5111808u) { src = w2; dst = w2b; off = i4 - 3932160u; }
    else if (i4 < 7471104u) { src = w3; dst = w3b; off = i4 - 5111808u; }
    else if (i4 < 9830400u) { src = w4; dst = w4b; off = i4 - 7471104u; }
    else                    { src = w5; dst = w5b; off = i4 - 9830400u; }
    float4 v = *reinterpret_cast<const float4*>(src + off);
    ushort4 u;
    u.x = f2b(v.x); u.y = f2b(v.y); u.z = f2b(v.z); u.w = f2b(v.w);
    *reinterpret_cast<ushort4*>(dst + off) = u;
}

// ---------------------------------------------------------------------------
// Causal depthwise conv(4) + bias + SiLU; reads bf16 xz (stride 2*DI).
// ---------------------------------------------------------------------------
__global__ __launch_bounds__(256)
void conv_silu_k(const unsigned short* __restrict__ xz, const float* __restrict__ cw,
                 const float* __restrict__ cb, unsigned short* __restrict__ xcb)
{
    int q = blockIdx.x * 256 + threadIdx.x;
    int d4 = (q * 4) % DI;
    int bt = (q * 4) / DI;
    int t  = bt % SEQ;
    const unsigned short* base = xz + (size_t)bt * (2 * DI) + d4;
    float4 acc = *reinterpret_cast<const float4*>(cb + d4);
    float4 wv0 = *reinterpret_cast<const float4*>(cw + (d4 + 0) * 4);
    float4 wv1 = *reinterpret_cast<const float4*>(cw + (d4 + 1) * 4);
    float4 wv2 = *reinterpret_cast<const float4*>(cw + (d4 + 2) * 4);
    float4 wv3 = *reinterpret_cast<const float4*>(cw + (d4 + 3) * 4);
    {
        ushort4 r = *reinterpret_cast<const ushort4*>(base);
        acc.x += wv0.w * b2f(r.x); acc.y += wv1.w * b2f(r.y);
        acc.z += wv2.w * b2f(r.z); acc.w += wv3.w * b2f(r.w);
    }
    if (t >= 1) {
        ushort4 r = *reinterpret_cast<const ushort4*>(base - 2 * DI);
        acc.x += wv0.z * b2f(r.x); acc.y += wv1.z * b2f(r.y);
        acc.z += wv2.z * b2f(r.z); acc.w += wv3.z * b2f(r.w);
    }
    if (t >= 2) {
        ushort4 r = *reinterpret_cast<const ushort4*>(base - 4 * DI);
        acc.x += wv0.y * b2f(r.x); acc.y += wv1.y * b2f(r.y);
        acc.z += wv2.y * b2f(r.z); acc.w += wv3.y * b2f(r.w);
    }
    if (t >= 3) {
        ushort4 r = *reinterpret_cast<const ushort4*>(base - 6 * DI);
        acc.x += wv0.x * b2f(r.x); acc.y += wv1.x * b2f(r.y);
        acc.z += wv2.x * b2f(r.z); acc.w += wv3.x * b2f(r.w);
    }
    ushort4 u;
    u.x = f2b(acc.x / (1.f + __expf(-acc.x)));
    u.y = f2b(acc.y / (1.f + __expf(-acc.y)));
    u.z = f2b(acc.z / (1.f + __expf(-acc.z)));
    u.w = f2b(acc.w / (1.f + __expf(-acc.w)));
    *reinterpret_cast<ushort4*>(xcb + (size_t)bt * DI + d4) = u;
}

// ---------------------------------------------------------------------------
// scan3: persistent sequential-chunk scan. One wave (64 thr) per (16 d, b);
// grid (DI/16, BATCH) = 192 blocks. h carried in registers across chunks.
// Per chunk: regs->LDS, prefetch next chunk, dt_proj MFMA, 32-step scan,
// fused D-skip + SiLU(z) gate, coalesced bf16 y write.
// ---------------------------------------------------------------------------
__global__ __launch_bounds__(64)
void scan3(const unsigned short* __restrict__ xdblb, const unsigned short* __restrict__ wdtb,
           const float* __restrict__ dtb,  const unsigned short* __restrict__ xcb,
           const float* __restrict__ xdbl, const float* __restrict__ A_log,
           const float* __restrict__ Dp,   const unsigned short* __restrict__ xz,
           unsigned short* __restrict__ yb)
{
    const int d0 = blockIdx.x * 16, b = blockIdx.y;
    __shared__ float del_s[TCH][20];
    __shared__ unsigned short xd_s[TCH][72];
    __shared__ unsigned short xc_s[TCH][24];
    __shared__ unsigned short z_s[TCH][24];
    __shared__ float b_s[TCH][20];
    __shared__ float c_s[TCH][20];

    const int lane = threadIdx.x;          // single wave
    const int ln = lane & 15, lg = lane >> 4;
    const int wd = lane >> 2;              // 0..15
    const int nq = (lane & 3) * 4;
    const int d = d0 + wd;
    const int srow = lane >> 1, sh = lane & 1;   // staging: 32 rows x 2 halves

    // prefetch registers for one chunk
    u32x4 rxd[4], rxc, rzv;
    float4 rb[2], rc[2];

#define LOAD_REGS(ch) do { \
        size_t rr_ = (size_t)(b * SEQ + (ch) * TCH + srow); \
        _Pragma("unroll") \
        for (int j = 0; j < 4; ++j) \
            rxd[j] = *reinterpret_cast<const u32x4*>(&xdblb[rr_ * 64 + (size_t)(sh * 4 + j) * 8]); \
        rxc = *reinterpret_cast<const u32x4*>(&xcb[rr_ * DI + d0 + sh * 8]); \
        rzv = *reinterpret_cast<const u32x4*>(&xz[rr_ * (2 * DI) + DI + d0 + sh * 8]); \
        _Pragma("unroll") \
        for (int j = 0; j < 2; ++j) { \
            rb[j] = *reinterpret_cast<const float4*>(&xdbl[rr_ * 80 + 48 + (size_t)(sh * 2 + j) * 4]); \
            rc[j] = *reinterpret_cast<const float4*>(&xdbl[rr_ * 80 + 64 + (size_t)(sh * 2 + j) * 4]); \
        } \
    } while (0)

    LOAD_REGS(0);

    float4 Av = *reinterpret_cast<const float4*>(&A_log[d * DSTATE + nq]);
    const float A0 = -__expf(Av.x), A1 = -__expf(Av.y), A2 = -__expf(Av.z), A3 = -__expf(Av.w);
    const float Dd = Dp[d];
    const float bias_d = dtb[d0 + ln];
    const unsigned short* wrow = wdtb + (size_t)(d0 + ln) * 64;

    float4 h = {0.f, 0.f, 0.f, 0.f};

    for (int ch = 0; ch < NCH; ++ch) {
        __syncthreads();                       // prior scan done with LDS
        #pragma unroll
        for (int j = 0; j < 4; ++j)
            *reinterpret_cast<u32x4*>(&xd_s[srow][(sh * 4 + j) * 8]) = rxd[j];
        *reinterpret_cast<u32x4*>(&xc_s[srow][sh * 8]) = rxc;
        *reinterpret_cast<u32x4*>(&z_s[srow][sh * 8]) = rzv;
        #pragma unroll
        for (int j = 0; j < 2; ++j) {
            *reinterpret_cast<float4*>(&b_s[srow][(sh * 2 + j) * 4]) = rb[j];
            *reinterpret_cast<float4*>(&c_s[srow][(sh * 2 + j) * 4]) = rc[j];
        }
        __syncthreads();                       // LDS visible
        if (ch + 1 < NCH) LOAD_REGS(ch + 1);   // prefetch: hides under MFMA+scan

        // dt_proj: del_s[t][0..15] = softplus(xd @ wdt^T + b), 4 MFMAs
        {
            f32x4 dacc[2];
            dacc[0] = (f32x4){0.f, 0.f, 0.f, 0.f};
            dacc[1] = (f32x4){0.f, 0.f, 0.f, 0.f};
            #pragma unroll
            for (int kk = 0; kk < 2; ++kk) {
                bf16x8 wf = *reinterpret_cast<const bf16x8*>(wrow + kk * 32 + lg * 8);
                #pragma unroll
                for (int i = 0; i < 2; ++i) {
                    bf16x8 a = *reinterpret_cast<const bf16x8*>(&xd_s[i * 16 + ln][kk * 32 + lg * 8]);
                    dacc[i] = __builtin_amdgcn_mfma_f32_16x16x32_bf16(a, wf, dacc[i], 0, 0, 0);
                }
            }
            #pragma unroll
            for (int i = 0; i < 2; ++i)
                #pragma unroll
                for (int rr = 0; rr < 4; ++rr) {
                    float v = dacc[i][rr] + bias_d;
                    del_s[i * 16 + lg * 4 + rr][ln] = (v > 20.f) ? v : log1pf(__expf(v));
                }
        }
        __syncthreads();                       // del_s ready

        unsigned short* yrow = yb + (size_t)(b * SEQ + ch * TCH) * DI + d;
        #pragma unroll 4
        for (int t = 0; t < TCH; ++t) {
            float dl = del_s[t][wd];
            float xv = b2f(xc_s[t][wd]);
            float u  = dl * xv;
            float4 bq = *reinterpret_cast<const float4*>(&b_s[t][nq]);
            float4 cq = *reinterpret_cast<const float4*>(&c_s[t][nq]);
            float e0 = __expf(dl * A0), e1 = __expf(dl * A1);
            float e2 = __expf(dl * A2), e3 = __expf(dl * A3);
            h.x = e0 * h.x + u * bq.x;
            h.y = e1 * h.y + u * bq.y;
            h.z = e2 * h.z + u * bq.z;
            h.w = e3 * h.w + u * bq.w;
            float py = h.x * cq.x + h.y * cq.y + h.z * cq.z + h.w * cq.w;
            py += __shfl_xor(py, 1);
            py += __shfl_xor(py, 2);
            if ((lane & 3) == 0) {
                float yv = py + xv * Dd;
                float zv = b2f(z_s[t][wd]);
                yv *= zv / (1.f + __expf(-zv));
                yrow[(size_t)t * DI] = f2b(yv);
            }
        }
    }
#undef LOAD_REGS
}

// ---------------------------------------------------------------------------
extern "C" void kernel_launch(void* const* d_in, const int* in_sizes, int n_in,
                              void* d_out, int out_size, void* d_ws, size_t ws_size,
                              hipStream_t stream)
{
    const float* x         = (const float*)d_in[0];
    const float* in_proj_w = (const float*)d_in[1];
    const float* conv_w    = (const float*)d_in[2];
    const float* conv_b    = (const float*)d_in[3];
    const float* x_proj_w  = (const float*)d_in[4];
    const float* dt_proj_w = (const float*)d_in[5];
    const float* dt_proj_b = (const float*)d_in[6];
    const float* A_log     = (const float*)d_in[7];
    const float* D_param   = (const float*)d_in[8];
    const float* out_proj_w= (const float*)d_in[9];
    const float* ln1_w     = (const float*)d_in[10];
    const float* ln1_b     = (const float*)d_in[11];
    const float* ln2_w     = (const float*)d_in[12];
    const float* ln2_b     = (const float*)d_in[13];
    const float* ffn_w1    = (const float*)d_in[14];
    const float* ffn_b1    = (const float*)d_in[15];
    const float* ffn_w2    = (const float*)d_in[16];
    const float* ffn_b2    = (const float*)d_in[17];
    float* out = (float*)d_out;

    char* Wp = (char*)d_ws;
    #define MB(n) ((size_t)(n) * 1048576)
    unsigned short* xzb   = (unsigned short*)(Wp + 0);        // 12.6 MB
    unsigned short* xcb   = (unsigned short*)(Wp + MB(16));   // 6.3 MB
    float*          xdbl  = (float*)         (Wp + MB(24));   // 0.66 MB
    unsigned short* xdblb = (unsigned short*)(Wp + MB(26));   // 0.26 MB
    unsigned short* ybb   = (unsigned short*)(Wp + MB(28));   // 6.3 MB
    unsigned short* xb    = (unsigned short*)(Wp + MB(36));   // 3.1 MB
    unsigned short* wib   = (unsigned short*)(Wp + MB(40));   // 4.7 MB
    unsigned short* wob   = (unsigned short*)(Wp + MB(45));   // 2.4 MB
    unsigned short* wf1b  = (unsigned short*)(Wp + MB(48));   // 4.7 MB
    unsigned short* wf2b  = (unsigned short*)(Wp + MB(53));   // 4.7 MB
    unsigned short* xpwb  = (unsigned short*)(Wp + MB(58));   // 0.25 MB
    unsigned short* wdtb  = (unsigned short*)(Wp + MB(59));   // 0.19 MB
    float*          part  = (float*)         (Wp + MB(60));   // 5.3 MB
    float*          part_op = (float*)       (Wp + MB(66));   // 25.2 MB
    float*          part_f2 = (float*)       (Wp + MB(92));   // 25.2 MB
    float*          x1    = (float*)         (Wp + MB(118));  // 6.3 MB
    unsigned short* x1b   = (unsigned short*)(Wp + MB(125));  // 3.1 MB
    unsigned short* fbf   = (unsigned short*)(Wp + MB(129));  // 12.6 MB
    #undef MB

    dim3 blk(256);

    // 1. bf16 conversions (x + all weights)
    cvt7_k<<<9816, blk, 0, stream>>>(x, in_proj_w, out_proj_w, ffn_w1, ffn_w2, x_proj_w,
                                     dt_proj_w, xb, wib, wob, wf1b, wf2b, xpwb, wdtb);

    // 2. in_proj -> xzb bf16 [2048][3072]
    gemm_sk<6, 1><<<dim3(48, 16, 1), blk, 0, stream>>>(xb, wib, nullptr, xzb, nullptr,
                                                       NROWS, 2 * DI, EMBED, nullptr);

    // 3. conv + silu -> xcb bf16
    conv_silu_k<<<(BATCH * SEQ * DI) / 1024, blk, 0, stream>>>(xzb, conv_w, conv_b, xcb);

    // 4. x_proj split-K MFMA + reduce -> xdbl f32 + xdblb bf16(pad64)
    xproj_mfma<<<dim3(16, 8), blk, 0, stream>>>(xcb, xpwb, part);
    xproj_reduce<<<640, blk, 0, stream>>>(part, xdbl, xdblb);

    // 5. persistent sequential-chunk scan (fused dt_proj + gate) -> ybb
    scan3<<<dim3(DI / 16, BATCH), dim3(64), 0, stream>>>(
        xdblb, wdtb, dt_proj_b, xcb, xdbl, A_log, D_param, xzb, ybb);

    // 6. out_proj split-K(4) -> partials; fused reduce+resid+LN1 -> x1 + x1b
    gemm_sk<0, 4><<<dim3(12, 16, 4), blk, 0, stream>>>(ybb, wob, nullptr, nullptr, part_op,
                                                       NROWS, EMBED, DI, nullptr);
    reduce_ln<4, 0><<<NROWS, blk, 0, stream>>>(part_op, x, nullptr, ln1_w, ln1_b, x1, x1b);

    // 7. ffn1 + gelu -> fbf bf16
    gemm_sk<3, 1><<<dim3(48, 16, 1), blk, 0, stream>>>(x1b, wf1b, nullptr, fbf, nullptr,
                                                       NROWS, FF, EMBED, ffn_b1);

    // 8. ffn2 split-K(4) -> partials; fused reduce+bias+resid+LN2 -> out
    gemm_sk<0, 4><<<dim3(12, 16, 4), blk, 0, stream>>>(fbf, wf2b, nullptr, nullptr, part_f2,
                                                       NROWS, EMBED, FF, nullptr);
    reduce_ln<4, 1><<<NROWS, blk, 0, stream>>>(part_f2, x1, ffn_b2, ln2_w, ln2_b, out, nullptr);
}

// Round 15
// 201.360 us; speedup vs baseline: 2.1439x; 2.1439x over previous
//
#include <hip/hip_runtime.h>
#include <math.h>

#define EMBED 768
#define DI 1536
#define DSTATE 16
#define DCONV 4
#define DTRANK 48
#define FF 3072
#define BATCH 2
#define SEQ 1024
#define NROWS (BATCH*SEQ)
#define TCH 32
#define NCH (SEQ/TCH)
#define DBLK 64

typedef __bf16 bf16x8 __attribute__((ext_vector_type(8)));
typedef float f32x4 __attribute__((ext_vector_type(4)));
typedef unsigned int u32x4 __attribute__((ext_vector_type(4)));

static __device__ __forceinline__ unsigned short f2b(float f) {
    union { float f; unsigned u; } v; v.f = f;
    unsigned r = v.u + 0x7FFFu + ((v.u >> 16) & 1u);
    return (unsigned short)(r >> 16);
}
static __device__ __forceinline__ float b2f(unsigned short s) {
    union { unsigned u; float f; } v; v.u = ((unsigned)s) << 16;
    return v.f;
}

#define GLOAD_LDS16(g, l) __builtin_amdgcn_global_load_lds( \
    (const __attribute__((address_space(1))) void*)(g), \
    (__attribute__((address_space(3))) void*)(l), 16, 0, 0)

// ---------------------------------------------------------------------------
// gemm_sk: C[M,N] = A[M,K](bf16) @ W[N,K](bf16)^T, 128x64 tile, BK=32,
// 2-phase double-buffered global_load_lds staging.
// EPI: 3 gelu(acc+bias)->Cb bf16 ; 6 plain bf16 -> Cb ; KSPLIT>1 -> partials.
// ---------------------------------------------------------------------------
template<int EPI, int KSPLIT>
__global__ __launch_bounds__(256)
void gemm_sk(const unsigned short* __restrict__ A,
             const unsigned short* __restrict__ W,
             float* __restrict__ C, unsigned short* __restrict__ Cb,
             float* __restrict__ part,
             int M, int N, int K,
             const float* __restrict__ bias)
{
    __shared__ alignas(16) unsigned short As[2][128 * 32];
    __shared__ alignas(16) unsigned short Ws[2][64 * 32];
    const int tid  = threadIdx.x;
    const int lane = tid & 63, wave = tid >> 6;
    const int bm = blockIdx.y * 128, bn = blockIdx.x * 64;
    const int kc = K / KSPLIT;
    const int kz = blockIdx.z * kc;
    const int ln = lane & 15, lg = lane >> 4;

    f32x4 acc[2][4];
    #pragma unroll
    for (int i = 0; i < 2; ++i)
        #pragma unroll
        for (int j = 0; j < 4; ++j)
            acc[i][j] = (f32x4){0.f, 0.f, 0.f, 0.f};

    const int ra = tid >> 2, ca = tid & 3;
    const int cs = (ca * 8) ^ ((ra & 3) << 3);
    const unsigned short* gA0 = A + (size_t)(bm + ra) * K + kz + cs;
    const unsigned short* gA1 = A + (size_t)(bm + ra + 64) * K + kz + cs;
    const unsigned short* gW  = W + (size_t)(bn + ra) * K + kz + cs;

#define STAGE(bf, kk) do { \
        GLOAD_LDS16(gA0 + (kk), &As[bf][wave * 512]); \
        GLOAD_LDS16(gA1 + (kk), &As[bf][2048 + wave * 512]); \
        GLOAD_LDS16(gW  + (kk), &Ws[bf][wave * 512]); \
    } while (0)

    STAGE(0, 0);
    __syncthreads();
    int buf = 0;
    for (int k0 = 0; k0 < kc; k0 += 32) {
        if (k0 + 32 < kc) STAGE(buf ^ 1, k0 + 32);
        bf16x8 af[2], wf[4];
        #pragma unroll
        for (int i = 0; i < 2; ++i) {
            int row = wave * 32 + i * 16 + ln;
            af[i] = *reinterpret_cast<const bf16x8*>(
                &As[buf][row * 32 + ((lg * 8) ^ ((row & 3) << 3))]);
        }
        #pragma unroll
        for (int j = 0; j < 4; ++j) {
            int row = j * 16 + ln;
            wf[j] = *reinterpret_cast<const bf16x8*>(
                &Ws[buf][row * 32 + ((lg * 8) ^ ((row & 3) << 3))]);
        }
        #pragma unroll
        for (int i = 0; i < 2; ++i)
            #pragma unroll
            for (int j = 0; j < 4; ++j)
                acc[i][j] = __builtin_amdgcn_mfma_f32_16x16x32_bf16(af[i], wf[j], acc[i][j], 0, 0, 0);
        __syncthreads();
        buf ^= 1;
    }
#undef STAGE

    if constexpr (KSPLIT > 1) {
        float* pb = part + (size_t)blockIdx.z * M * N;
        #pragma unroll
        for (int i = 0; i < 2; ++i)
            #pragma unroll
            for (int j = 0; j < 4; ++j) {
                int col = bn + j * 16 + ln;
                #pragma unroll
                for (int rr = 0; rr < 4; ++rr) {
                    int row = bm + wave * 32 + i * 16 + lg * 4 + rr;
                    pb[(size_t)row * N + col] = acc[i][j][rr];
                }
            }
    } else {
        #pragma unroll
        for (int i = 0; i < 2; ++i)
            #pragma unroll
            for (int j = 0; j < 4; ++j) {
                int col = bn + j * 16 + ln;
                #pragma unroll
                for (int rr = 0; rr < 4; ++rr) {
                    int row = bm + wave * 32 + i * 16 + lg * 4 + rr;
                    float v = acc[i][j][rr];
                    size_t o = (size_t)row * N + col;
                    if (EPI == 3) {
                        v += bias[col];
                        float t = 0.7978845608028654f * (v + 0.044715f * v * v * v);
                        Cb[o] = f2b(0.5f * v * (1.f + tanhf(t)));
                    } else if (EPI == 6) {
                        Cb[o] = f2b(v);
                    } else {
                        C[o] = v;
                    }
                }
            }
    }
}

// ---------------------------------------------------------------------------
// reduce_ln: sum KS split-K partials (+bias) (+resid), then LayerNorm(768).
// ---------------------------------------------------------------------------
template<int KS, int BIAS>
__global__ __launch_bounds__(256)
void reduce_ln(const float* __restrict__ part, const float* __restrict__ resid,
               const float* __restrict__ bias,
               const float* __restrict__ w, const float* __restrict__ bb,
               float* __restrict__ out, unsigned short* __restrict__ outb)
{
    const int row = blockIdx.x;
    const size_t ro = (size_t)row * EMBED;
    const int i0 = threadIdx.x, i1 = i0 + 256, i2 = i0 + 512;
    float v0 = 0.f, v1 = 0.f, v2 = 0.f;
    #pragma unroll
    for (int z = 0; z < KS; ++z) {
        const float* p = part + (size_t)z * NROWS * EMBED + ro;
        v0 += p[i0]; v1 += p[i1]; v2 += p[i2];
    }
    if (BIAS) { v0 += bias[i0]; v1 += bias[i1]; v2 += bias[i2]; }
    v0 += resid[ro + i0]; v1 += resid[ro + i1]; v2 += resid[ro + i2];

    float s  = v0 + v1 + v2;
    float s2 = v0 * v0 + v1 * v1 + v2 * v2;
    #pragma unroll
    for (int m = 1; m < 64; m <<= 1) {
        s  += __shfl_xor(s,  m);
        s2 += __shfl_xor(s2, m);
    }
    __shared__ float sh1[4], sh2[4];
    int wv = threadIdx.x >> 6;
    if ((threadIdx.x & 63) == 0) { sh1[wv] = s; sh2[wv] = s2; }
    __syncthreads();
    float S1 = sh1[0] + sh1[1] + sh1[2] + sh1[3];
    float S2 = sh2[0] + sh2[1] + sh2[2] + sh2[3];
    float mu  = S1 * (1.f / EMBED);
    float var = S2 * (1.f / EMBED) - mu * mu;
    float rs  = rsqrtf(var + 1e-5f);
    float o0 = (v0 - mu) * rs * w[i0] + bb[i0];
    float o1 = (v1 - mu) * rs * w[i1] + bb[i1];
    float o2 = (v2 - mu) * rs * w[i2] + bb[i2];
    out[ro + i0] = o0; out[ro + i1] = o1; out[ro + i2] = o2;
    if (outb) {
        outb[ro + i0] = f2b(o0); outb[ro + i1] = f2b(o1); outb[ro + i2] = f2b(o2);
    }
}

// ---------------------------------------------------------------------------
// x_proj split-K MFMA + reduce
// ---------------------------------------------------------------------------
__global__ __launch_bounds__(256)
void xproj_mfma(const unsigned short* __restrict__ A,
                const unsigned short* __restrict__ W,
                float* __restrict__ part)
{
    const int mt = blockIdx.x, s = blockIdx.y;
    const int lane = threadIdx.x & 63, wave = threadIdx.x >> 6;
    const int ln = lane & 15, lg = lane >> 4;
    const int row0 = mt * 128 + wave * 32;
    const int kb = s * 192;
    f32x4 acc[2][5];
    #pragma unroll
    for (int i = 0; i < 2; ++i)
        #pragma unroll
        for (int j = 0; j < 5; ++j)
            acc[i][j] = (f32x4){0.f, 0.f, 0.f, 0.f};

    for (int kk = 0; kk < 192; kk += 32) {
        const int k = kb + kk + lg * 8;
        bf16x8 af[2], wf[5];
        af[0] = *reinterpret_cast<const bf16x8*>(A + (size_t)(row0 + ln) * DI + k);
        af[1] = *reinterpret_cast<const bf16x8*>(A + (size_t)(row0 + 16 + ln) * DI + k);
        #pragma unroll
        for (int j = 0; j < 5; ++j)
            wf[j] = *reinterpret_cast<const bf16x8*>(W + (size_t)(j * 16 + ln) * DI + k);
        #pragma unroll
        for (int i = 0; i < 2; ++i)
            #pragma unroll
            for (int j = 0; j < 5; ++j)
                acc[i][j] = __builtin_amdgcn_mfma_f32_16x16x32_bf16(af[i], wf[j], acc[i][j], 0, 0, 0);
    }
    float* pb = part + (size_t)s * NROWS * 80;
    #pragma unroll
    for (int i = 0; i < 2; ++i)
        #pragma unroll
        for (int j = 0; j < 5; ++j)
            #pragma unroll
            for (int rr = 0; rr < 4; ++rr) {
                int row = row0 + i * 16 + lg * 4 + rr;
                int col = j * 16 + ln;
                pb[(size_t)row * 80 + col] = acc[i][j][rr];
            }
}

__global__ __launch_bounds__(256)
void xproj_reduce(const float* __restrict__ part, float* __restrict__ xdbl,
                  unsigned short* __restrict__ xdblb)
{
    int idx = blockIdx.x * 256 + threadIdx.x;      // 163840
    float sum = 0.f;
    #pragma unroll
    for (int s = 0; s < 8; ++s) sum += part[(size_t)s * NROWS * 80 + idx];
    xdbl[idx] = sum;
    int col = idx % 80, row = idx / 80;
    if (col < 48)      xdblb[row * 64 + col] = f2b(sum);
    else if (col < 64) xdblb[row * 64 + col] = 0;
}

// ---------------------------------------------------------------------------
// f32 -> bf16 conversion: x + 4 big weights + x_proj_w + padded dt_proj_w.
// ---------------------------------------------------------------------------
__global__ __launch_bounds__(256)
void cvt7_k(const float* __restrict__ x,  const float* __restrict__ w1,
            const float* __restrict__ w2, const float* __restrict__ w3,
            const float* __restrict__ w4, const float* __restrict__ w5,
            const float* __restrict__ w6,
            unsigned short* __restrict__ xb,  unsigned short* __restrict__ w1b,
            unsigned short* __restrict__ w2b, unsigned short* __restrict__ w3b,
            unsigned short* __restrict__ w4b, unsigned short* __restrict__ w5b,
            unsigned short* __restrict__ w6b)
{
    size_t i4 = ((size_t)blockIdx.x * 256 + threadIdx.x) * 4;
    if (i4 >= 9953280u) {
        int off = (int)(i4 - 9953280u);
        if (off >= 98304) return;
        int row = off >> 6, colb = off & 63;
        ushort4 u = {0, 0, 0, 0};
        if (colb < 48) {
            float4 v = *reinterpret_cast<const float4*>(w6 + row * 48 + colb);
            u.x = f2b(v.x); u.y = f2b(v.y); u.z = f2b(v.z); u.w = f2b(v.w);
        }
        *reinterpret_cast<ushort4*>(w6b + off) = u;
        return;
    }
    const float* src; unsigned short* dst; size_t off;
    if      (i4 < 1572864u) { src = x;  dst = xb;  off = i4; }
    else if (i4 < 3932160u) { src = w1; dst = w1b; off = i4 - 1572864u; }
    else if (i4 < 5111808u) { src = w2; dst = w2b; off = i4 - 3932160u; }
    else if (i4 < 7471104u) { src = w3; dst = w3b; off = i4 - 5111808u; }
    else if (i4 < 9830400u) { src = w4; dst = w4b; off = i4 - 7471104u; }
    else                    { src = w5; dst = w5b; off = i4 - 9830400u; }
    float4 v = *reinterpret_cast<const float4*>(src + off);
    ushort4 u;
    u.x = f2b(v.x); u.y = f2b(v.y); u.z = f2b(v.z); u.w = f2b(v.w);
    *reinterpret_cast<ushort4*>(dst + off) = u;
}

// ---------------------------------------------------------------------------
// Causal depthwise conv(4) + bias + SiLU; reads bf16 xz (stride 2*DI).
// ---------------------------------------------------------------------------
__global__ __launch_bounds__(256)
void conv_silu_k(const unsigned short* __restrict__ xz, const float* __restrict__ cw,
                 const float* __restrict__ cb, unsigned short* __restrict__ xcb)
{
    int q = blockIdx.x * 256 + threadIdx.x;
    int d4 = (q * 4) % DI;
    int bt = (q * 4) / DI;
    int t  = bt % SEQ;
    const unsigned short* base = xz + (size_t)bt * (2 * DI) + d4;
    float4 acc = *reinterpret_cast<const float4*>(cb + d4);
    float4 wv0 = *reinterpret_cast<const float4*>(cw + (d4 + 0) * 4);
    float4 wv1 = *reinterpret_cast<const float4*>(cw + (d4 + 1) * 4);
    float4 wv2 = *reinterpret_cast<const float4*>(cw + (d4 + 2) * 4);
    float4 wv3 = *reinterpret_cast<const float4*>(cw + (d4 + 3) * 4);
    {
        ushort4 r = *reinterpret_cast<const ushort4*>(base);
        acc.x += wv0.w * b2f(r.x); acc.y += wv1.w * b2f(r.y);
        acc.z += wv2.w * b2f(r.z); acc.w += wv3.w * b2f(r.w);
    }
    if (t >= 1) {
        ushort4 r = *reinterpret_cast<const ushort4*>(base - 2 * DI);
        acc.x += wv0.z * b2f(r.x); acc.y += wv1.z * b2f(r.y);
        acc.z += wv2.z * b2f(r.z); acc.w += wv3.z * b2f(r.w);
    }
    if (t >= 2) {
        ushort4 r = *reinterpret_cast<const ushort4*>(base - 4 * DI);
        acc.x += wv0.y * b2f(r.x); acc.y += wv1.y * b2f(r.y);
        acc.z += wv2.y * b2f(r.z); acc.w += wv3.y * b2f(r.w);
    }
    if (t >= 3) {
        ushort4 r = *reinterpret_cast<const ushort4*>(base - 6 * DI);
        acc.x += wv0.x * b2f(r.x); acc.y += wv1.x * b2f(r.y);
        acc.z += wv2.x * b2f(r.z); acc.w += wv3.x * b2f(r.w);
    }
    ushort4 u;
    u.x = f2b(acc.x / (1.f + __expf(-acc.x)));
    u.y = f2b(acc.y / (1.f + __expf(-acc.y)));
    u.z = f2b(acc.z / (1.f + __expf(-acc.z)));
    u.w = f2b(acc.w / (1.f + __expf(-acc.w)));
    *reinterpret_cast<ushort4*>(xcb + (size_t)bt * DI + d4) = u;
}

// ---------------------------------------------------------------------------
// In-scan dt_proj: del_s[32][DBLK] = softplus(xd_s @ wdtb_slice^T + b)
// via 4 MFMAs/wave. C layout: row=t (lg*4+rr), col=d (wave*16+ln).
// ---------------------------------------------------------------------------
static __device__ __forceinline__ void dt_mfma(
    const unsigned short (*xd_s)[72], float (*del_s)[DBLK + 4],
    const unsigned short* __restrict__ wdtb, const float* __restrict__ dtb,
    int d0, int wave, int ln, int lg)
{
    f32x4 dacc[2];
    dacc[0] = (f32x4){0.f, 0.f, 0.f, 0.f};
    dacc[1] = (f32x4){0.f, 0.f, 0.f, 0.f};
    const unsigned short* wrow = wdtb + (size_t)(d0 + wave * 16 + ln) * 64;
    #pragma unroll
    for (int kk = 0; kk < 2; ++kk) {
        bf16x8 wf = *reinterpret_cast<const bf16x8*>(wrow + kk * 32 + lg * 8);
        #pragma unroll
        for (int i = 0; i < 2; ++i) {
            bf16x8 a = *reinterpret_cast<const bf16x8*>(&xd_s[i * 16 + ln][kk * 32 + lg * 8]);
            dacc[i] = __builtin_amdgcn_mfma_f32_16x16x32_bf16(a, wf, dacc[i], 0, 0, 0);
        }
    }
    float bias_d = dtb[d0 + wave * 16 + ln];
    #pragma unroll
    for (int i = 0; i < 2; ++i)
        #pragma unroll
        for (int rr = 0; rr < 4; ++rr) {
            float v = dacc[i][rr] + bias_d;
            del_s[i * 16 + lg * 4 + rr][wave * 16 + ln] =
                (v > 20.f) ? v : log1pf(__expf(v));
        }
}

// ---------------------------------------------------------------------------
// scan2_a: fused dt_proj + per-chunk local scan (TCH=32), n-quad per thread.
// ---------------------------------------------------------------------------
__global__ __launch_bounds__(256)
void scan2_a(const unsigned short* __restrict__ xdblb, const unsigned short* __restrict__ wdtb,
             const float* __restrict__ dtb,  const unsigned short* __restrict__ xcb,
             const float* __restrict__ xdbl, const float* __restrict__ A_log,
             float* __restrict__ hfin, float* __restrict__ aprod)
{
    const int d0 = blockIdx.x * DBLK, ch = blockIdx.y, b = blockIdx.z;
    const int t0 = ch * TCH;
    __shared__ float del_s[TCH][DBLK + 4];
    __shared__ unsigned short xd_s[TCH][72];
    __shared__ unsigned short xc_s[TCH][DBLK + 8];
    __shared__ float b_s[TCH][20];
    const int tid = threadIdx.x;
    {
        const int cz = tid & 7, tz = tid >> 3;
        size_t rz = (size_t)(b * SEQ + t0 + tz);
        *reinterpret_cast<u32x4*>(&xc_s[tz][cz * 8]) =
            *reinterpret_cast<const u32x4*>(&xcb[rz * DI + d0 + cz * 8]);
        *reinterpret_cast<u32x4*>(&xd_s[tz][cz * 8]) =
            *reinterpret_cast<const u32x4*>(&xdblb[rz * 64 + cz * 8]);
        const int cbq = tid & 3, tb = tid >> 2;
        if (tb < TCH) {
            size_t rowo = (size_t)(b * SEQ + t0 + tb);
            *reinterpret_cast<float4*>(&b_s[tb][cbq * 4]) =
                *reinterpret_cast<const float4*>(&xdbl[rowo * 80 + DTRANK + cbq * 4]);
        }
    }
    __syncthreads();
    const int lane = tid & 63, wave = tid >> 6;
    const int ln = lane & 15, lg = lane >> 4;
    dt_mfma(xd_s, del_s, wdtb, dtb, d0, wave, ln, lg);
    __syncthreads();

    const int wd = wave * 16 + (lane >> 2);
    const int d = d0 + wd;
    const int nq = (lane & 3) * 4;
    float4 Av = *reinterpret_cast<const float4*>(&A_log[d * DSTATE + nq]);
    const float A0 = -__expf(Av.x), A1 = -__expf(Av.y), A2 = -__expf(Av.z), A3 = -__expf(Av.w);
    float h0_ = 0.f, h1_ = 0.f, h2_ = 0.f, h3_ = 0.f;
    float p0 = 1.f, p1 = 1.f, p2 = 1.f, p3 = 1.f;
    #pragma unroll 4
    for (int t = 0; t < TCH; ++t) {
        float dl = del_s[t][wd];
        float u  = dl * b2f(xc_s[t][wd]);
        float4 bq = *reinterpret_cast<const float4*>(&b_s[t][nq]);
        float e0 = __expf(dl * A0), e1 = __expf(dl * A1);
        float e2 = __expf(dl * A2), e3 = __expf(dl * A3);
        h0_ = e0 * h0_ + u * bq.x; p0 *= e0;
        h1_ = e1 * h1_ + u * bq.y; p1 *= e1;
        h2_ = e2 * h2_ + u * bq.z; p2 *= e2;
        h3_ = e3 * h3_ + u * bq.w; p3 *= e3;
    }
    size_t o = ((size_t)((b * NCH + ch) * DI) + d) * DSTATE + nq;
    *reinterpret_cast<float4*>(&hfin[o])  = (float4){h0_, h1_, h2_, h3_};
    *reinterpret_cast<float4*>(&aprod[o]) = (float4){p0, p1, p2, p3};
}

// ---------------------------------------------------------------------------
// scan2_b: serial combine over chunks, float4 per thread (one n-quad).
// ---------------------------------------------------------------------------
__global__ __launch_bounds__(256)
void scan2_b(const float* __restrict__ hfin, const float* __restrict__ aprod,
             float* __restrict__ h0)
{
    int idx = blockIdx.x * 256 + threadIdx.x;      // B*DI*4 = 12288
    int nq = (idx & 3) * 4;
    int d  = (idx >> 2) % DI;
    int b  = (idx >> 2) / DI;
    float4 h = {0.f, 0.f, 0.f, 0.f};
    #pragma unroll
    for (int ch = 0; ch < NCH; ++ch) {
        size_t o = ((size_t)((b * NCH + ch) * DI) + d) * DSTATE + nq;
        *reinterpret_cast<float4*>(&h0[o]) = h;
        float4 a = *reinterpret_cast<const float4*>(&aprod[o]);
        float4 f = *reinterpret_cast<const float4*>(&hfin[o]);
        h.x = a.x * h.x + f.x; h.y = a.y * h.y + f.y;
        h.z = a.z * h.z + f.z; h.w = a.w * h.w + f.w;
    }
}

// ---------------------------------------------------------------------------
// scan2_c: fused dt_proj + full scan from h0 + reduce + gate (TCH=32).
// ---------------------------------------------------------------------------
__global__ __launch_bounds__(256)
void scan2_c(const unsigned short* __restrict__ xdblb, const unsigned short* __restrict__ wdtb,
             const float* __restrict__ dtb,  const unsigned short* __restrict__ xcb,
             const float* __restrict__ xdbl, const float* __restrict__ A_log,
             const float* __restrict__ Dp,   const unsigned short* __restrict__ xz,
             const float* __restrict__ h0,
             unsigned short* __restrict__ yb)
{
    const int d0 = blockIdx.x * DBLK, ch = blockIdx.y, b = blockIdx.z;
    const int t0 = ch * TCH;
    __shared__ float del_s[TCH][DBLK + 4];
    __shared__ unsigned short xd_s[TCH][72];
    __shared__ unsigned short xc_s[TCH][DBLK + 8];
    __shared__ float b_s[TCH][20];
    __shared__ float c_s[TCH][20];
    __shared__ unsigned short z_s[TCH][DBLK + 8];
    const int tid = threadIdx.x;
    {
        const int cz = tid & 7, tz = tid >> 3;
        size_t rz = (size_t)(b * SEQ + t0 + tz);
        *reinterpret_cast<u32x4*>(&xc_s[tz][cz * 8]) =
            *reinterpret_cast<const u32x4*>(&xcb[rz * DI + d0 + cz * 8]);
        *reinterpret_cast<u32x4*>(&z_s[tz][cz * 8]) =
            *reinterpret_cast<const u32x4*>(&xz[rz * (2 * DI) + DI + d0 + cz * 8]);
        *reinterpret_cast<u32x4*>(&xd_s[tz][cz * 8]) =
            *reinterpret_cast<const u32x4*>(&xdblb[rz * 64 + cz * 8]);
        const int cbq = tid & 3, tb = tid >> 2;
        if (tb < TCH) {
            size_t rowo = (size_t)(b * SEQ + t0 + tb);
            *reinterpret_cast<float4*>(&b_s[tb][cbq * 4]) =
                *reinterpret_cast<const float4*>(&xdbl[rowo * 80 + DTRANK + cbq * 4]);
        } else {
            size_t rowo = (size_t)(b * SEQ + t0 + tb - TCH);
            *reinterpret_cast<float4*>(&c_s[tb - TCH][cbq * 4]) =
                *reinterpret_cast<const float4*>(&xdbl[rowo * 80 + DTRANK + DSTATE + cbq * 4]);
        }
    }
    const int lane = tid & 63, wave = tid >> 6;
    const int ln = lane & 15, lg = lane >> 4;
    const int wd = wave * 16 + (lane >> 2);
    const int d = d0 + wd;
    const int nq = (lane & 3) * 4;

    // h0 load: single independent float4, overlaps staging
    float4 h = *reinterpret_cast<const float4*>(
        &h0[((size_t)((b * NCH + ch) * DI) + d) * DSTATE + nq]);

    __syncthreads();
    dt_mfma(xd_s, del_s, wdtb, dtb, d0, wave, ln, lg);
    __syncthreads();

    float4 Av = *reinterpret_cast<const float4*>(&A_log[d * DSTATE + nq]);
    const float A0 = -__expf(Av.x), A1 = -__expf(Av.y), A2 = -__expf(Av.z), A3 = -__expf(Av.w);
    const float Dd = Dp[d];
    unsigned short* yrow = yb + (size_t)(b * SEQ + t0) * DI + d;
    #pragma unroll 4
    for (int t = 0; t < TCH; ++t) {
        float dl = del_s[t][wd];
        float xv = b2f(xc_s[t][wd]);
        float u  = dl * xv;
        float4 bq = *reinterpret_cast<const float4*>(&b_s[t][nq]);
        float4 cq = *reinterpret_cast<const float4*>(&c_s[t][nq]);
        float e0 = __expf(dl * A0), e1 = __expf(dl * A1);
        float e2 = __expf(dl * A2), e3 = __expf(dl * A3);
        h.x = e0 * h.x + u * bq.x;
        h.y = e1 * h.y + u * bq.y;
        h.z = e2 * h.z + u * bq.z;
        h.w = e3 * h.w + u * bq.w;
        float py = h.x * cq.x + h.y * cq.y + h.z * cq.z + h.w * cq.w;
        py += __shfl_xor(py, 1);
        py += __shfl_xor(py, 2);
        if ((lane & 3) == 0) {
            float yv = py + xv * Dd;
            float zv = b2f(z_s[t][wd]);
            yv *= zv / (1.f + __expf(-zv));
            yrow[(size_t)t * DI] = f2b(yv);
        }
    }
}

// ---------------------------------------------------------------------------
extern "C" void kernel_launch(void* const* d_in, const int* in_sizes, int n_in,
                              void* d_out, int out_size, void* d_ws, size_t ws_size,
                              hipStream_t stream)
{
    const float* x         = (const float*)d_in[0];
    const float* in_proj_w = (const float*)d_in[1];
    const float* conv_w    = (const float*)d_in[2];
    const float* conv_b    = (const float*)d_in[3];
    const float* x_proj_w  = (const float*)d_in[4];
    const float* dt_proj_w = (const float*)d_in[5];
    const float* dt_proj_b = (const float*)d_in[6];
    const float* A_log     = (const float*)d_in[7];
    const float* D_param   = (const float*)d_in[8];
    const float* out_proj_w= (const float*)d_in[9];
    const float* ln1_w     = (const float*)d_in[10];
    const float* ln1_b     = (const float*)d_in[11];
    const float* ln2_w     = (const float*)d_in[12];
    const float* ln2_b     = (const float*)d_in[13];
    const float* ffn_w1    = (const float*)d_in[14];
    const float* ffn_b1    = (const float*)d_in[15];
    const float* ffn_w2    = (const float*)d_in[16];
    const float* ffn_b2    = (const float*)d_in[17];
    float* out = (float*)d_out;

    char* Wp = (char*)d_ws;
    #define MB(n) ((size_t)(n) * 1048576)
    unsigned short* xzb   = (unsigned short*)(Wp + 0);        // 12.6 MB
    unsigned short* xcb   = (unsigned short*)(Wp + MB(16));   // 6.3 MB
    float*          xdbl  = (float*)         (Wp + MB(24));   // 0.66 MB
    unsigned short* xdblb = (unsigned short*)(Wp + MB(26));   // 0.26 MB
    unsigned short* ybb   = (unsigned short*)(Wp + MB(28));   // 6.3 MB
    float*          hfin  = (float*)         (Wp + MB(36));   // 6.3 MB
    float*          aprod = (float*)         (Wp + MB(44));   // 6.3 MB
    float*          h0    = (float*)         (Wp + MB(52));   // 6.3 MB
    unsigned short* xb    = (unsigned short*)(Wp + MB(60));   // 3.1 MB
    unsigned short* wib   = (unsigned short*)(Wp + MB(64));   // 4.7 MB
    unsigned short* wob   = (unsigned short*)(Wp + MB(69));   // 2.4 MB
    unsigned short* wf1b  = (unsigned short*)(Wp + MB(72));   // 4.7 MB
    unsigned short* wf2b  = (unsigned short*)(Wp + MB(77));   // 4.7 MB
    unsigned short* xpwb  = (unsigned short*)(Wp + MB(82));   // 0.25 MB
    unsigned short* wdtb  = (unsigned short*)(Wp + MB(83));   // 0.19 MB
    float*          part  = (float*)         (Wp + MB(84));   // 5.3 MB
    float*          part_op = (float*)       (Wp + MB(90));   // 25.2 MB
    float*          part_f2 = (float*)       (Wp + MB(116));  // 25.2 MB
    float*          x1    = (float*)         (Wp + MB(142));  // 6.3 MB
    unsigned short* x1b   = (unsigned short*)(Wp + MB(149));  // 3.1 MB
    unsigned short* fbf   = (unsigned short*)(Wp + MB(153));  // 12.6 MB
    #undef MB

    dim3 blk(256);

    // 1. bf16 conversions (x + all weights)
    cvt7_k<<<9816, blk, 0, stream>>>(x, in_proj_w, out_proj_w, ffn_w1, ffn_w2, x_proj_w,
                                     dt_proj_w, xb, wib, wob, wf1b, wf2b, xpwb, wdtb);

    // 2. in_proj -> xzb bf16 [2048][3072]
    gemm_sk<6, 1><<<dim3(48, 16, 1), blk, 0, stream>>>(xb, wib, nullptr, xzb, nullptr,
                                                       NROWS, 2 * DI, EMBED, nullptr);

    // 3. conv + silu -> xcb bf16
    conv_silu_k<<<(BATCH * SEQ * DI) / 1024, blk, 0, stream>>>(xzb, conv_w, conv_b, xcb);

    // 4. x_proj split-K MFMA + reduce -> xdbl f32 + xdblb bf16(pad64)
    xproj_mfma<<<dim3(16, 8), blk, 0, stream>>>(xcb, xpwb, part);
    xproj_reduce<<<640, blk, 0, stream>>>(part, xdbl, xdblb);

    // 5+6. chunked scan with fused dt_proj (TCH=32); prefix in scan2_b
    scan2_a<<<dim3(DI / DBLK, NCH, BATCH), blk, 0, stream>>>(
        xdblb, wdtb, dt_proj_b, xcb, xdbl, A_log, hfin, aprod);
    scan2_b<<<48, blk, 0, stream>>>(hfin, aprod, h0);
    scan2_c<<<dim3(DI / DBLK, NCH, BATCH), blk, 0, stream>>>(
        xdblb, wdtb, dt_proj_b, xcb, xdbl, A_log, D_param, xzb, h0, ybb);

    // 8. out_proj split-K(4) -> partials; fused reduce+resid+LN1 -> x1 + x1b
    gemm_sk<0, 4><<<dim3(12, 16, 4), blk, 0, stream>>>(ybb, wob, nullptr, nullptr, part_op,
                                                       NROWS, EMBED, DI, nullptr);
    reduce_ln<4, 0><<<NROWS, blk, 0, stream>>>(part_op, x, nullptr, ln1_w, ln1_b, x1, x1b);

    // 10. ffn1 + gelu -> fbf bf16
    gemm_sk<3, 1><<<dim3(48, 16, 1), blk, 0, stream>>>(x1b, wf1b, nullptr, fbf, nullptr,
                                                       NROWS, FF, EMBED, ffn_b1);

    // 11. ffn2 split-K(4) -> partials; fused reduce+bias+resid+LN2 -> out
    gemm_sk<0, 4><<<dim3(12, 16, 4), blk, 0, stream>>>(fbf, wf2b, nullptr, nullptr, part_f2,
                                                       NROWS, EMBED, FF, nullptr);
    reduce_ln<4, 1><<<NROWS, blk, 0, stream>>>(part_f2, x1, ffn_b2, ln2_w, ln2_b, out, nullptr);
}

// Round 16
// 196.187 us; speedup vs baseline: 2.2004x; 1.0264x over previous
//
#include <hip/hip_runtime.h>
#include <math.h>

#define EMBED 768
#define DI 1536
#define DSTATE 16
#define DCONV 4
#define DTRANK 48
#define FF 3072
#define BATCH 2
#define SEQ 1024
#define NROWS (BATCH*SEQ)
#define TCH 32
#define NCH (SEQ/TCH)
#define DBLK 64

typedef __bf16 bf16x8 __attribute__((ext_vector_type(8)));
typedef float f32x4 __attribute__((ext_vector_type(4)));
typedef unsigned int u32x4 __attribute__((ext_vector_type(4)));

static __device__ __forceinline__ unsigned short f2b(float f) {
    union { float f; unsigned u; } v; v.f = f;
    unsigned r = v.u + 0x7FFFu + ((v.u >> 16) & 1u);
    return (unsigned short)(r >> 16);
}
static __device__ __forceinline__ float b2f(unsigned short s) {
    union { unsigned u; float f; } v; v.u = ((unsigned)s) << 16;
    return v.f;
}

#define GLOAD_LDS16(g, l) __builtin_amdgcn_global_load_lds( \
    (const __attribute__((address_space(1))) void*)(g), \
    (__attribute__((address_space(3))) void*)(l), 16, 0, 0)

// ---------------------------------------------------------------------------
// gemm_sk: C[M,N] = A[M,K](bf16) @ W[N,K](bf16)^T, 128x64 tile, BK=32,
// 2-phase double-buffered global_load_lds staging, XCD-aware block swizzle
// (requires grid size % 8 == 0; all call sites satisfy this).
// EPI: 3 gelu(acc+bias)->Cb bf16 ; 6 plain bf16 -> Cb ; KSPLIT>1 -> partials.
// ---------------------------------------------------------------------------
template<int EPI, int KSPLIT>
__global__ __launch_bounds__(256)
void gemm_sk(const unsigned short* __restrict__ A,
             const unsigned short* __restrict__ W,
             float* __restrict__ C, unsigned short* __restrict__ Cb,
             float* __restrict__ part,
             int M, int N, int K,
             const float* __restrict__ bias)
{
    __shared__ alignas(16) unsigned short As[2][128 * 32];
    __shared__ alignas(16) unsigned short Ws[2][64 * 32];
    const int tid  = threadIdx.x;
    const int lane = tid & 63, wave = tid >> 6;

    // XCD-aware swizzle: contiguous logical tiles per XCD (bijective, nwg%8==0)
    const int gx = gridDim.x, gy = gridDim.y;
    const int nwg = gx * gy * gridDim.z;
    const int bid = blockIdx.x + gx * (blockIdx.y + gy * blockIdx.z);
    const int wg  = (bid & 7) * (nwg >> 3) + (bid >> 3);
    const int bxi = wg % gx;
    const int byi = (wg / gx) % gy;
    const int bzi = wg / (gx * gy);

    const int bm = byi * 128, bn = bxi * 64;
    const int kc = K / KSPLIT;
    const int kz = bzi * kc;
    const int ln = lane & 15, lg = lane >> 4;

    f32x4 acc[2][4];
    #pragma unroll
    for (int i = 0; i < 2; ++i)
        #pragma unroll
        for (int j = 0; j < 4; ++j)
            acc[i][j] = (f32x4){0.f, 0.f, 0.f, 0.f};

    const int ra = tid >> 2, ca = tid & 3;
    const int cs = (ca * 8) ^ ((ra & 3) << 3);
    const unsigned short* gA0 = A + (size_t)(bm + ra) * K + kz + cs;
    const unsigned short* gA1 = A + (size_t)(bm + ra + 64) * K + kz + cs;
    const unsigned short* gW  = W + (size_t)(bn + ra) * K + kz + cs;

#define STAGE(bf, kk) do { \
        GLOAD_LDS16(gA0 + (kk), &As[bf][wave * 512]); \
        GLOAD_LDS16(gA1 + (kk), &As[bf][2048 + wave * 512]); \
        GLOAD_LDS16(gW  + (kk), &Ws[bf][wave * 512]); \
    } while (0)

    STAGE(0, 0);
    __syncthreads();
    int buf = 0;
    for (int k0 = 0; k0 < kc; k0 += 32) {
        if (k0 + 32 < kc) STAGE(buf ^ 1, k0 + 32);
        bf16x8 af[2], wf[4];
        #pragma unroll
        for (int i = 0; i < 2; ++i) {
            int row = wave * 32 + i * 16 + ln;
            af[i] = *reinterpret_cast<const bf16x8*>(
                &As[buf][row * 32 + ((lg * 8) ^ ((row & 3) << 3))]);
        }
        #pragma unroll
        for (int j = 0; j < 4; ++j) {
            int row = j * 16 + ln;
            wf[j] = *reinterpret_cast<const bf16x8*>(
                &Ws[buf][row * 32 + ((lg * 8) ^ ((row & 3) << 3))]);
        }
        #pragma unroll
        for (int i = 0; i < 2; ++i)
            #pragma unroll
            for (int j = 0; j < 4; ++j)
                acc[i][j] = __builtin_amdgcn_mfma_f32_16x16x32_bf16(af[i], wf[j], acc[i][j], 0, 0, 0);
        __syncthreads();
        buf ^= 1;
    }
#undef STAGE

    if constexpr (KSPLIT > 1) {
        float* pb = part + (size_t)bzi * M * N;
        #pragma unroll
        for (int i = 0; i < 2; ++i)
            #pragma unroll
            for (int j = 0; j < 4; ++j) {
                int col = bn + j * 16 + ln;
                #pragma unroll
                for (int rr = 0; rr < 4; ++rr) {
                    int row = bm + wave * 32 + i * 16 + lg * 4 + rr;
                    pb[(size_t)row * N + col] = acc[i][j][rr];
                }
            }
    } else {
        #pragma unroll
        for (int i = 0; i < 2; ++i)
            #pragma unroll
            for (int j = 0; j < 4; ++j) {
                int col = bn + j * 16 + ln;
                #pragma unroll
                for (int rr = 0; rr < 4; ++rr) {
                    int row = bm + wave * 32 + i * 16 + lg * 4 + rr;
                    float v = acc[i][j][rr];
                    size_t o = (size_t)row * N + col;
                    if (EPI == 3) {
                        v += bias[col];
                        float t = 0.7978845608028654f * (v + 0.044715f * v * v * v);
                        Cb[o] = f2b(0.5f * v * (1.f + tanhf(t)));
                    } else if (EPI == 6) {
                        Cb[o] = f2b(v);
                    } else {
                        C[o] = v;
                    }
                }
            }
    }
}

// ---------------------------------------------------------------------------
// reduce_ln: sum KS split-K partials (+bias) (+resid), then LayerNorm(768).
// ---------------------------------------------------------------------------
template<int KS, int BIAS>
__global__ __launch_bounds__(256)
void reduce_ln(const float* __restrict__ part, const float* __restrict__ resid,
               const float* __restrict__ bias,
               const float* __restrict__ w, const float* __restrict__ bb,
               float* __restrict__ out, unsigned short* __restrict__ outb)
{
    const int row = blockIdx.x;
    const size_t ro = (size_t)row * EMBED;
    const int i0 = threadIdx.x, i1 = i0 + 256, i2 = i0 + 512;
    float v0 = 0.f, v1 = 0.f, v2 = 0.f;
    #pragma unroll
    for (int z = 0; z < KS; ++z) {
        const float* p = part + (size_t)z * NROWS * EMBED + ro;
        v0 += p[i0]; v1 += p[i1]; v2 += p[i2];
    }
    if (BIAS) { v0 += bias[i0]; v1 += bias[i1]; v2 += bias[i2]; }
    v0 += resid[ro + i0]; v1 += resid[ro + i1]; v2 += resid[ro + i2];

    float s  = v0 + v1 + v2;
    float s2 = v0 * v0 + v1 * v1 + v2 * v2;
    #pragma unroll
    for (int m = 1; m < 64; m <<= 1) {
        s  += __shfl_xor(s,  m);
        s2 += __shfl_xor(s2, m);
    }
    __shared__ float sh1[4], sh2[4];
    int wv = threadIdx.x >> 6;
    if ((threadIdx.x & 63) == 0) { sh1[wv] = s; sh2[wv] = s2; }
    __syncthreads();
    float S1 = sh1[0] + sh1[1] + sh1[2] + sh1[3];
    float S2 = sh2[0] + sh2[1] + sh2[2] + sh2[3];
    float mu  = S1 * (1.f / EMBED);
    float var = S2 * (1.f / EMBED) - mu * mu;
    float rs  = rsqrtf(var + 1e-5f);
    float o0 = (v0 - mu) * rs * w[i0] + bb[i0];
    float o1 = (v1 - mu) * rs * w[i1] + bb[i1];
    float o2 = (v2 - mu) * rs * w[i2] + bb[i2];
    out[ro + i0] = o0; out[ro + i1] = o1; out[ro + i2] = o2;
    if (outb) {
        outb[ro + i0] = f2b(o0); outb[ro + i1] = f2b(o1); outb[ro + i2] = f2b(o2);
    }
}

// ---------------------------------------------------------------------------
// x_proj split-K MFMA + reduce (XCD swizzle: 128 blocks, nwg%8==0)
// ---------------------------------------------------------------------------
__global__ __launch_bounds__(256)
void xproj_mfma(const unsigned short* __restrict__ A,
                const unsigned short* __restrict__ W,
                float* __restrict__ part)
{
    const int gx = gridDim.x;
    const int nwg = gx * gridDim.y;
    const int bid = blockIdx.x + gx * blockIdx.y;
    const int wg  = (bid & 7) * (nwg >> 3) + (bid >> 3);
    const int mt = wg % gx, s = wg / gx;
    const int lane = threadIdx.x & 63, wave = threadIdx.x >> 6;
    const int ln = lane & 15, lg = lane >> 4;
    const int row0 = mt * 128 + wave * 32;
    const int kb = s * 192;
    f32x4 acc[2][5];
    #pragma unroll
    for (int i = 0; i < 2; ++i)
        #pragma unroll
        for (int j = 0; j < 5; ++j)
            acc[i][j] = (f32x4){0.f, 0.f, 0.f, 0.f};

    for (int kk = 0; kk < 192; kk += 32) {
        const int k = kb + kk + lg * 8;
        bf16x8 af[2], wf[5];
        af[0] = *reinterpret_cast<const bf16x8*>(A + (size_t)(row0 + ln) * DI + k);
        af[1] = *reinterpret_cast<const bf16x8*>(A + (size_t)(row0 + 16 + ln) * DI + k);
        #pragma unroll
        for (int j = 0; j < 5; ++j)
            wf[j] = *reinterpret_cast<const bf16x8*>(W + (size_t)(j * 16 + ln) * DI + k);
        #pragma unroll
        for (int i = 0; i < 2; ++i)
            #pragma unroll
            for (int j = 0; j < 5; ++j)
                acc[i][j] = __builtin_amdgcn_mfma_f32_16x16x32_bf16(af[i], wf[j], acc[i][j], 0, 0, 0);
    }
    float* pb = part + (size_t)s * NROWS * 80;
    #pragma unroll
    for (int i = 0; i < 2; ++i)
        #pragma unroll
        for (int j = 0; j < 5; ++j)
            #pragma unroll
            for (int rr = 0; rr < 4; ++rr) {
                int row = row0 + i * 16 + lg * 4 + rr;
                int col = j * 16 + ln;
                pb[(size_t)row * 80 + col] = acc[i][j][rr];
            }
}

__global__ __launch_bounds__(256)
void xproj_reduce(const float* __restrict__ part, float* __restrict__ xdbl,
                  unsigned short* __restrict__ xdblb)
{
    int idx = blockIdx.x * 256 + threadIdx.x;      // 163840
    float sum = 0.f;
    #pragma unroll
    for (int s = 0; s < 8; ++s) sum += part[(size_t)s * NROWS * 80 + idx];
    xdbl[idx] = sum;
    int col = idx % 80, row = idx / 80;
    if (col < 48)      xdblb[row * 64 + col] = f2b(sum);
    else if (col < 64) xdblb[row * 64 + col] = 0;
}

// ---------------------------------------------------------------------------
// f32 -> bf16 conversion: x + 4 big weights + x_proj_w + padded dt_proj_w.
// ---------------------------------------------------------------------------
__global__ __launch_bounds__(256)
void cvt7_k(const float* __restrict__ x,  const float* __restrict__ w1,
            const float* __restrict__ w2, const float* __restrict__ w3,
            const float* __restrict__ w4, const float* __restrict__ w5,
            const float* __restrict__ w6,
            unsigned short* __restrict__ xb,  unsigned short* __restrict__ w1b,
            unsigned short* __restrict__ w2b, unsigned short* __restrict__ w3b,
            unsigned short* __restrict__ w4b, unsigned short* __restrict__ w5b,
            unsigned short* __restrict__ w6b)
{
    size_t i4 = ((size_t)blockIdx.x * 256 + threadIdx.x) * 4;
    if (i4 >= 9953280u) {
        int off = (int)(i4 - 9953280u);
        if (off >= 98304) return;
        int row = off >> 6, colb = off & 63;
        ushort4 u = {0, 0, 0, 0};
        if (colb < 48) {
            float4 v = *reinterpret_cast<const float4*>(w6 + row * 48 + colb);
            u.x = f2b(v.x); u.y = f2b(v.y); u.z = f2b(v.z); u.w = f2b(v.w);
        }
        *reinterpret_cast<ushort4*>(w6b + off) = u;
        return;
    }
    const float* src; unsigned short* dst; size_t off;
    if      (i4 < 1572864u) { src = x;  dst = xb;  off = i4; }
    else if (i4 < 3932160u) { src = w1; dst = w1b; off = i4 - 1572864u; }
    else if (i4 < 5111808u) { src = w2; dst = w2b; off = i4 - 3932160u; }
    else if (i4 < 7471104u) { src = w3; dst = w3b; off = i4 - 5111808u; }
    else if (i4 < 9830400u) { src = w4; dst = w4b; off = i4 - 7471104u; }
    else                    { src = w5; dst = w5b; off = i4 - 9830400u; }
    float4 v = *reinterpret_cast<const float4*>(src + off);
    ushort4 u;
    u.x = f2b(v.x); u.y = f2b(v.y); u.z = f2b(v.z); u.w = f2b(v.w);
    *reinterpret_cast<ushort4*>(dst + off) = u;
}

// ---------------------------------------------------------------------------
// Causal depthwise conv(4) + bias + SiLU; reads bf16 xz (stride 2*DI).
// ---------------------------------------------------------------------------
__global__ __launch_bounds__(256)
void conv_silu_k(const unsigned short* __restrict__ xz, const float* __restrict__ cw,
                 const float* __restrict__ cb, unsigned short* __restrict__ xcb)
{
    int q = blockIdx.x * 256 + threadIdx.x;
    int d4 = (q * 4) % DI;
    int bt = (q * 4) / DI;
    int t  = bt % SEQ;
    const unsigned short* base = xz + (size_t)bt * (2 * DI) + d4;
    float4 acc = *reinterpret_cast<const float4*>(cb + d4);
    float4 wv0 = *reinterpret_cast<const float4*>(cw + (d4 + 0) * 4);
    float4 wv1 = *reinterpret_cast<const float4*>(cw + (d4 + 1) * 4);
    float4 wv2 = *reinterpret_cast<const float4*>(cw + (d4 + 2) * 4);
    float4 wv3 = *reinterpret_cast<const float4*>(cw + (d4 + 3) * 4);
    {
        ushort4 r = *reinterpret_cast<const ushort4*>(base);
        acc.x += wv0.w * b2f(r.x); acc.y += wv1.w * b2f(r.y);
        acc.z += wv2.w * b2f(r.z); acc.w += wv3.w * b2f(r.w);
    }
    if (t >= 1) {
        ushort4 r = *reinterpret_cast<const ushort4*>(base - 2 * DI);
        acc.x += wv0.z * b2f(r.x); acc.y += wv1.z * b2f(r.y);
        acc.z += wv2.z * b2f(r.z); acc.w += wv3.z * b2f(r.w);
    }
    if (t >= 2) {
        ushort4 r = *reinterpret_cast<const ushort4*>(base - 4 * DI);
        acc.x += wv0.y * b2f(r.x); acc.y += wv1.y * b2f(r.y);
        acc.z += wv2.y * b2f(r.z); acc.w += wv3.y * b2f(r.w);
    }
    if (t >= 3) {
        ushort4 r = *reinterpret_cast<const ushort4*>(base - 6 * DI);
        acc.x += wv0.x * b2f(r.x); acc.y += wv1.x * b2f(r.y);
        acc.z += wv2.x * b2f(r.z); acc.w += wv3.x * b2f(r.w);
    }
    ushort4 u;
    u.x = f2b(acc.x / (1.f + __expf(-acc.x)));
    u.y = f2b(acc.y / (1.f + __expf(-acc.y)));
    u.z = f2b(acc.z / (1.f + __expf(-acc.z)));
    u.w = f2b(acc.w / (1.f + __expf(-acc.w)));
    *reinterpret_cast<ushort4*>(xcb + (size_t)bt * DI + d4) = u;
}

// ---------------------------------------------------------------------------
// In-scan dt_proj: del_s[32][DBLK] = softplus(xd_s @ wdtb_slice^T + b)
// via 4 MFMAs/wave. C layout: row=t (lg*4+rr), col=d (wave*16+ln).
// ---------------------------------------------------------------------------
static __device__ __forceinline__ void dt_mfma(
    const unsigned short (*xd_s)[72], float (*del_s)[DBLK + 4],
    const unsigned short* __restrict__ wdtb, const float* __restrict__ dtb,
    int d0, int wave, int ln, int lg)
{
    f32x4 dacc[2];
    dacc[0] = (f32x4){0.f, 0.f, 0.f, 0.f};
    dacc[1] = (f32x4){0.f, 0.f, 0.f, 0.f};
    const unsigned short* wrow = wdtb + (size_t)(d0 + wave * 16 + ln) * 64;
    #pragma unroll
    for (int kk = 0; kk < 2; ++kk) {
        bf16x8 wf = *reinterpret_cast<const bf16x8*>(wrow + kk * 32 + lg * 8);
        #pragma unroll
        for (int i = 0; i < 2; ++i) {
            bf16x8 a = *reinterpret_cast<const bf16x8*>(&xd_s[i * 16 + ln][kk * 32 + lg * 8]);
            dacc[i] = __builtin_amdgcn_mfma_f32_16x16x32_bf16(a, wf, dacc[i], 0, 0, 0);
        }
    }
    float bias_d = dtb[d0 + wave * 16 + ln];
    #pragma unroll
    for (int i = 0; i < 2; ++i)
        #pragma unroll
        for (int rr = 0; rr < 4; ++rr) {
            float v = dacc[i][rr] + bias_d;
            del_s[i * 16 + lg * 4 + rr][wave * 16 + ln] =
                (v > 20.f) ? v : log1pf(__expf(v));
        }
}

// ---------------------------------------------------------------------------
// scan2_a: fused dt_proj + per-chunk local scan (TCH=32), n-quad per thread.
// ---------------------------------------------------------------------------
__global__ __launch_bounds__(256)
void scan2_a(const unsigned short* __restrict__ xdblb, const unsigned short* __restrict__ wdtb,
             const float* __restrict__ dtb,  const unsigned short* __restrict__ xcb,
             const float* __restrict__ xdbl, const float* __restrict__ A_log,
             float* __restrict__ hfin, float* __restrict__ aprod)
{
    const int d0 = blockIdx.x * DBLK, ch = blockIdx.y, b = blockIdx.z;
    const int t0 = ch * TCH;
    __shared__ float del_s[TCH][DBLK + 4];
    __shared__ unsigned short xd_s[TCH][72];
    __shared__ unsigned short xc_s[TCH][DBLK + 8];
    __shared__ float b_s[TCH][20];
    const int tid = threadIdx.x;
    {
        const int cz = tid & 7, tz = tid >> 3;
        size_t rz = (size_t)(b * SEQ + t0 + tz);
        *reinterpret_cast<u32x4*>(&xc_s[tz][cz * 8]) =
            *reinterpret_cast<const u32x4*>(&xcb[rz * DI + d0 + cz * 8]);
        *reinterpret_cast<u32x4*>(&xd_s[tz][cz * 8]) =
            *reinterpret_cast<const u32x4*>(&xdblb[rz * 64 + cz * 8]);
        const int cbq = tid & 3, tb = tid >> 2;
        if (tb < TCH) {
            size_t rowo = (size_t)(b * SEQ + t0 + tb);
            *reinterpret_cast<float4*>(&b_s[tb][cbq * 4]) =
                *reinterpret_cast<const float4*>(&xdbl[rowo * 80 + DTRANK + cbq * 4]);
        }
    }
    __syncthreads();
    const int lane = tid & 63, wave = tid >> 6;
    const int ln = lane & 15, lg = lane >> 4;
    dt_mfma(xd_s, del_s, wdtb, dtb, d0, wave, ln, lg);
    __syncthreads();

    const int wd = wave * 16 + (lane >> 2);
    const int d = d0 + wd;
    const int nq = (lane & 3) * 4;
    float4 Av = *reinterpret_cast<const float4*>(&A_log[d * DSTATE + nq]);
    const float A0 = -__expf(Av.x), A1 = -__expf(Av.y), A2 = -__expf(Av.z), A3 = -__expf(Av.w);
    float h0_ = 0.f, h1_ = 0.f, h2_ = 0.f, h3_ = 0.f;
    float p0 = 1.f, p1 = 1.f, p2 = 1.f, p3 = 1.f;
    #pragma unroll 4
    for (int t = 0; t < TCH; ++t) {
        float dl = del_s[t][wd];
        float u  = dl * b2f(xc_s[t][wd]);
        float4 bq = *reinterpret_cast<const float4*>(&b_s[t][nq]);
        float e0 = __expf(dl * A0), e1 = __expf(dl * A1);
        float e2 = __expf(dl * A2), e3 = __expf(dl * A3);
        h0_ = e0 * h0_ + u * bq.x; p0 *= e0;
        h1_ = e1 * h1_ + u * bq.y; p1 *= e1;
        h2_ = e2 * h2_ + u * bq.z; p2 *= e2;
        h3_ = e3 * h3_ + u * bq.w; p3 *= e3;
    }
    size_t o = ((size_t)((b * NCH + ch) * DI) + d) * DSTATE + nq;
    *reinterpret_cast<float4*>(&hfin[o])  = (float4){h0_, h1_, h2_, h3_};
    *reinterpret_cast<float4*>(&aprod[o]) = (float4){p0, p1, p2, p3};
}

// ---------------------------------------------------------------------------
// scan2_b: serial combine over chunks, float4 per thread (one n-quad).
// ---------------------------------------------------------------------------
__global__ __launch_bounds__(256)
void scan2_b(const float* __restrict__ hfin, const float* __restrict__ aprod,
             float* __restrict__ h0)
{
    int idx = blockIdx.x * 256 + threadIdx.x;      // B*DI*4 = 12288
    int nq = (idx & 3) * 4;
    int d  = (idx >> 2) % DI;
    int b  = (idx >> 2) / DI;
    float4 h = {0.f, 0.f, 0.f, 0.f};
    #pragma unroll
    for (int ch = 0; ch < NCH; ++ch) {
        size_t o = ((size_t)((b * NCH + ch) * DI) + d) * DSTATE + nq;
        *reinterpret_cast<float4*>(&h0[o]) = h;
        float4 a = *reinterpret_cast<const float4*>(&aprod[o]);
        float4 f = *reinterpret_cast<const float4*>(&hfin[o]);
        h.x = a.x * h.x + f.x; h.y = a.y * h.y + f.y;
        h.z = a.z * h.z + f.z; h.w = a.w * h.w + f.w;
    }
}

// ---------------------------------------------------------------------------
// scan2_c: fused dt_proj + full scan from h0 + reduce + gate (TCH=32).
// ---------------------------------------------------------------------------
__global__ __launch_bounds__(256)
void scan2_c(const unsigned short* __restrict__ xdblb, const unsigned short* __restrict__ wdtb,
             const float* __restrict__ dtb,  const unsigned short* __restrict__ xcb,
             const float* __restrict__ xdbl, const float* __restrict__ A_log,
             const float* __restrict__ Dp,   const unsigned short* __restrict__ xz,
             const float* __restrict__ h0,
             unsigned short* __restrict__ yb)
{
    const int d0 = blockIdx.x * DBLK, ch = blockIdx.y, b = blockIdx.z;
    const int t0 = ch * TCH;
    __shared__ float del_s[TCH][DBLK + 4];
    __shared__ unsigned short xd_s[TCH][72];
    __shared__ unsigned short xc_s[TCH][DBLK + 8];
    __shared__ float b_s[TCH][20];
    __shared__ float c_s[TCH][20];
    __shared__ unsigned short z_s[TCH][DBLK + 8];
    const int tid = threadIdx.x;
    {
        const int cz = tid & 7, tz = tid >> 3;
        size_t rz = (size_t)(b * SEQ + t0 + tz);
        *reinterpret_cast<u32x4*>(&xc_s[tz][cz * 8]) =
            *reinterpret_cast<const u32x4*>(&xcb[rz * DI + d0 + cz * 8]);
        *reinterpret_cast<u32x4*>(&z_s[tz][cz * 8]) =
            *reinterpret_cast<const u32x4*>(&xz[rz * (2 * DI) + DI + d0 + cz * 8]);
        *reinterpret_cast<u32x4*>(&xd_s[tz][cz * 8]) =
            *reinterpret_cast<const u32x4*>(&xdblb[rz * 64 + cz * 8]);
        const int cbq = tid & 3, tb = tid >> 2;
        if (tb < TCH) {
            size_t rowo = (size_t)(b * SEQ + t0 + tb);
            *reinterpret_cast<float4*>(&b_s[tb][cbq * 4]) =
                *reinterpret_cast<const float4*>(&xdbl[rowo * 80 + DTRANK + cbq * 4]);
        } else {
            size_t rowo = (size_t)(b * SEQ + t0 + tb - TCH);
            *reinterpret_cast<float4*>(&c_s[tb - TCH][cbq * 4]) =
                *reinterpret_cast<const float4*>(&xdbl[rowo * 80 + DTRANK + DSTATE + cbq * 4]);
        }
    }
    const int lane = tid & 63, wave = tid >> 6;
    const int ln = lane & 15, lg = lane >> 4;
    const int wd = wave * 16 + (lane >> 2);
    const int d = d0 + wd;
    const int nq = (lane & 3) * 4;

    // h0 load: single independent float4, overlaps staging
    float4 h = *reinterpret_cast<const float4*>(
        &h0[((size_t)((b * NCH + ch) * DI) + d) * DSTATE + nq]);

    __syncthreads();
    dt_mfma(xd_s, del_s, wdtb, dtb, d0, wave, ln, lg);
    __syncthreads();

    float4 Av = *reinterpret_cast<const float4*>(&A_log[d * DSTATE + nq]);
    const float A0 = -__expf(Av.x), A1 = -__expf(Av.y), A2 = -__expf(Av.z), A3 = -__expf(Av.w);
    const float Dd = Dp[d];
    unsigned short* yrow = yb + (size_t)(b * SEQ + t0) * DI + d;
    #pragma unroll 4
    for (int t = 0; t < TCH; ++t) {
        float dl = del_s[t][wd];
        float xv = b2f(xc_s[t][wd]);
        float u  = dl * xv;
        float4 bq = *reinterpret_cast<const float4*>(&b_s[t][nq]);
        float4 cq = *reinterpret_cast<const float4*>(&c_s[t][nq]);
        float e0 = __expf(dl * A0), e1 = __expf(dl * A1);
        float e2 = __expf(dl * A2), e3 = __expf(dl * A3);
        h.x = e0 * h.x + u * bq.x;
        h.y = e1 * h.y + u * bq.y;
        h.z = e2 * h.z + u * bq.z;
        h.w = e3 * h.w + u * bq.w;
        float py = h.x * cq.x + h.y * cq.y + h.z * cq.z + h.w * cq.w;
        py += __shfl_xor(py, 1);
        py += __shfl_xor(py, 2);
        if ((lane & 3) == 0) {
            float yv = py + xv * Dd;
            float zv = b2f(z_s[t][wd]);
            yv *= zv / (1.f + __expf(-zv));
            yrow[(size_t)t * DI] = f2b(yv);
        }
    }
}

// ---------------------------------------------------------------------------
extern "C" void kernel_launch(void* const* d_in, const int* in_sizes, int n_in,
                              void* d_out, int out_size, void* d_ws, size_t ws_size,
                              hipStream_t stream)
{
    const float* x         = (const float*)d_in[0];
    const float* in_proj_w = (const float*)d_in[1];
    const float* conv_w    = (const float*)d_in[2];
    const float* conv_b    = (const float*)d_in[3];
    const float* x_proj_w  = (const float*)d_in[4];
    const float* dt_proj_w = (const float*)d_in[5];
    const float* dt_proj_b = (const float*)d_in[6];
    const float* A_log     = (const float*)d_in[7];
    const float* D_param   = (const float*)d_in[8];
    const float* out_proj_w= (const float*)d_in[9];
    const float* ln1_w     = (const float*)d_in[10];
    const float* ln1_b     = (const float*)d_in[11];
    const float* ln2_w     = (const float*)d_in[12];
    const float* ln2_b     = (const float*)d_in[13];
    const float* ffn_w1    = (const float*)d_in[14];
    const float* ffn_b1    = (const float*)d_in[15];
    const float* ffn_w2    = (const float*)d_in[16];
    const float* ffn_b2    = (const float*)d_in[17];
    float* out = (float*)d_out;

    char* Wp = (char*)d_ws;
    #define MB(n) ((size_t)(n) * 1048576)
    unsigned short* xzb   = (unsigned short*)(Wp + 0);        // 12.6 MB
    unsigned short* xcb   = (unsigned short*)(Wp + MB(16));   // 6.3 MB
    float*          xdbl  = (float*)         (Wp + MB(24));   // 0.66 MB
    unsigned short* xdblb = (unsigned short*)(Wp + MB(26));   // 0.26 MB
    unsigned short* ybb   = (unsigned short*)(Wp + MB(28));   // 6.3 MB
    float*          hfin  = (float*)         (Wp + MB(36));   // 6.3 MB
    float*          aprod = (float*)         (Wp + MB(44));   // 6.3 MB
    float*          h0    = (float*)         (Wp + MB(52));   // 6.3 MB
    unsigned short* xb    = (unsigned short*)(Wp + MB(60));   // 3.1 MB
    unsigned short* wib   = (unsigned short*)(Wp + MB(64));   // 4.7 MB
    unsigned short* wob   = (unsigned short*)(Wp + MB(69));   // 2.4 MB
    unsigned short* wf1b  = (unsigned short*)(Wp + MB(72));   // 4.7 MB
    unsigned short* wf2b  = (unsigned short*)(Wp + MB(77));   // 4.7 MB
    unsigned short* xpwb  = (unsigned short*)(Wp + MB(82));   // 0.25 MB
    unsigned short* wdtb  = (unsigned short*)(Wp + MB(83));   // 0.19 MB
    float*          part  = (float*)         (Wp + MB(84));   // 5.3 MB
    float*          part_op = (float*)       (Wp + MB(90));   // 25.2 MB
    float*          part_f2 = (float*)       (Wp + MB(116));  // 25.2 MB
    float*          x1    = (float*)         (Wp + MB(142));  // 6.3 MB
    unsigned short* x1b   = (unsigned short*)(Wp + MB(149));  // 3.1 MB
    unsigned short* fbf   = (unsigned short*)(Wp + MB(153));  // 12.6 MB
    #undef MB

    dim3 blk(256);

    // 1. bf16 conversions (x + all weights)
    cvt7_k<<<9816, blk, 0, stream>>>(x, in_proj_w, out_proj_w, ffn_w1, ffn_w2, x_proj_w,
                                     dt_proj_w, xb, wib, wob, wf1b, wf2b, xpwb, wdtb);

    // 2. in_proj -> xzb bf16 [2048][3072]
    gemm_sk<6, 1><<<dim3(48, 16, 1), blk, 0, stream>>>(xb, wib, nullptr, xzb, nullptr,
                                                       NROWS, 2 * DI, EMBED, nullptr);

    // 3. conv + silu -> xcb bf16
    conv_silu_k<<<(BATCH * SEQ * DI) / 1024, blk, 0, stream>>>(xzb, conv_w, conv_b, xcb);

    // 4. x_proj split-K MFMA + reduce -> xdbl f32 + xdblb bf16(pad64)
    xproj_mfma<<<dim3(16, 8), blk, 0, stream>>>(xcb, xpwb, part);
    xproj_reduce<<<640, blk, 0, stream>>>(part, xdbl, xdblb);

    // 5+6. chunked scan with fused dt_proj (TCH=32); prefix in scan2_b
    scan2_a<<<dim3(DI / DBLK, NCH, BATCH), blk, 0, stream>>>(
        xdblb, wdtb, dt_proj_b, xcb, xdbl, A_log, hfin, aprod);
    scan2_b<<<48, blk, 0, stream>>>(hfin, aprod, h0);
    scan2_c<<<dim3(DI / DBLK, NCH, BATCH), blk, 0, stream>>>(
        xdblb, wdtb, dt_proj_b, xcb, xdbl, A_log, D_param, xzb, h0, ybb);

    // 8. out_proj split-K(4) -> partials; fused reduce+resid+LN1 -> x1 + x1b
    gemm_sk<0, 4><<<dim3(12, 16, 4), blk, 0, stream>>>(ybb, wob, nullptr, nullptr, part_op,
                                                       NROWS, EMBED, DI, nullptr);
    reduce_ln<4, 0><<<NROWS, blk, 0, stream>>>(part_op, x, nullptr, ln1_w, ln1_b, x1, x1b);

    // 10. ffn1 + gelu -> fbf bf16
    gemm_sk<3, 1><<<dim3(48, 16, 1), blk, 0, stream>>>(x1b, wf1b, nullptr, fbf, nullptr,
                                                       NROWS, FF, EMBED, ffn_b1);

    // 11. ffn2 split-K(4) -> partials; fused reduce+bias+resid+LN2 -> out
    gemm_sk<0, 4><<<dim3(12, 16, 4), blk, 0, stream>>>(fbf, wf2b, nullptr, nullptr, part_f2,
                                                       NROWS, EMBED, FF, nullptr);
    reduce_ln<4, 1><<<NROWS, blk, 0, stream>>>(part_f2, x1, ffn_b2, ln2_w, ln2_b, out, nullptr);
}